// Round 3
// baseline (456.067 us; speedup 1.0000x reference)
//
#include <hip/hip_runtime.h>

// AttentionHead  B=4, T=2048, C=1024, HEAD=2048, fp32 in/out.
// Round 2: REVERT the LDS xor-swizzle (round-1 post-mortem: SQ_LDS_BANK_CONFLICT
// is invariant => conflicts are from global_load_lds's fixed lane-contiguous LDS
// writes, not the fragment reads; swizzle only broke global coalescing and added
// +32 VGPR). Keep: Vt-fused qkv epilogue, compact gemm_s grid, gemm_o longest-first.

#define T_    2048
#define C_    1024
#define B_    4
#define N3    6144
#define SCALE 0.03125f   // C^-0.5 = 1/32 exactly

typedef __attribute__((ext_vector_type(4))) float floatx4;
typedef __attribute__((ext_vector_type(8))) short short8;

__device__ __forceinline__ unsigned short f2bf(float f) {
  unsigned int u = __float_as_uint(f);
  unsigned int r = (u + 0x7fffu + ((u >> 16) & 1u)) >> 16;  // RNE
  return (unsigned short)r;
}

// ---------------------------------------------------------------- cast x
__global__ void cast_x_kernel(const float* __restrict__ x, ushort* __restrict__ xbf) {
  int i = blockIdx.x * 256 + threadIdx.x;          // over N/4 = 2097152
  float4 v = ((const float4*)x)[i];
  ushort4 o;
  o.x = f2bf(v.x); o.y = f2bf(v.y); o.z = f2bf(v.z); o.w = f2bf(v.w);
  ((ushort4*)xbf)[i] = o;
}

// ------------------------------------------- cast + transpose W -> WtT[n][k]
__global__ void wcast_t_kernel(const float* __restrict__ Wq, const float* __restrict__ Wk,
                               const float* __restrict__ Wv, ushort* __restrict__ WtT) {
  int k0 = blockIdx.x * 32;           // over C=1024
  int n0 = blockIdx.y * 32;           // over N3=6144
  const float* W = (n0 < 2048) ? Wq : (n0 < 4096 ? Wk : Wv);
  int nl0 = n0 & 2047;
  __shared__ ushort tile[32][33];
  int tx = threadIdx.x, ty = threadIdx.y;
  for (int r = ty; r < 32; r += 8)
    tile[r][tx] = f2bf(W[(size_t)(k0 + r) * 2048 + nl0 + tx]);
  __syncthreads();
  for (int r = ty; r < 32; r += 8)
    WtT[(size_t)(n0 + r) * 1024 + k0 + tx] = tile[tx][r];
}

// ---------------------------------------------------------------- bias concat
__global__ void bias_cat_kernel(const float* __restrict__ bq, const float* __restrict__ bk,
                                const float* __restrict__ bv, float* __restrict__ bcat) {
  int i = blockIdx.x * 256 + threadIdx.x;
  if (i < N3) {
    const float* s = (i < 2048) ? bq : (i < 4096 ? bk : bv);
    bcat[i] = s[i & 2047];
  }
}

// ------------------------------------------------------- GEMM core (m97 BT)
// Stage a 128x32 bf16 tile (rows K-contiguous, leading dim ld) into LDS
// [128 rows][32 k] via global_load_lds width=16. LDS dest is wave-uniform
// base + lane*16 -> layout must be (and is) exactly row-major unpadded.
// NOTE (r1 post-mortem): do NOT xor-swizzle here — SQ_LDS_BANK_CONFLICT is
// invariant (write-side), and swizzled global addrs cost +18% FETCH, +32 VGPR.
__device__ __forceinline__ void stage128x32(const ushort* g, int ld, char* lds,
                                            int wave, int lane) {
#pragma unroll
  for (int c = 0; c < 2; ++c) {
    int chunk = wave + 4 * c;                       // 8 chunks of 16 rows
    const ushort* gaddr = g + (size_t)(chunk * 16 + (lane >> 2)) * ld + (lane & 3) * 8;
    char* laddr = lds + chunk * 1024;               // wave-uniform
    __builtin_amdgcn_global_load_lds((const __attribute__((address_space(1))) unsigned int*)gaddr,
                                     (__attribute__((address_space(3))) unsigned int*)laddr,
                                     16, 0, 0);
  }
}

__device__ __forceinline__ void gemm_core(const ushort* A, int lda,
                                          const ushort* Bm, int ldb, int ksteps,
                                          char* ldsA, char* ldsB, floatx4 acc[4][4]) {
  int tid = threadIdx.x;
  int wave = tid >> 6, lane = tid & 63;
  int wm = wave >> 1, wn = wave & 1;
  int koff2 = ((lane >> 4) * 8) * 2;   // byte offset of k-fragment
  int rbase = lane & 15;
  for (int s = 0; s < ksteps; ++s) {
    __syncthreads();                              // LDS reads of prev iter done
    stage128x32(A + s * 32, lda, ldsA, wave, lane);
    stage128x32(Bm + s * 32, ldb, ldsB, wave, lane);
    __syncthreads();                              // vmcnt drain before reads
    short8 af[4], bf[4];
#pragma unroll
    for (int i = 0; i < 4; ++i) {
      af[i] = *(const short8*)(ldsA + (wm * 64 + i * 16 + rbase) * 64 + koff2);
      bf[i] = *(const short8*)(ldsB + (wn * 64 + i * 16 + rbase) * 64 + koff2);
    }
#pragma unroll
    for (int i = 0; i < 4; ++i)
#pragma unroll
      for (int j = 0; j < 4; ++j)
        acc[i][j] = __builtin_amdgcn_mfma_f32_16x16x32_bf16(af[i], bf[j], acc[i][j], 0, 0, 0);
  }
}

// -------------------------------------------------------------- GEMM: QKV
// Q,K thirds -> QKV row-major [s][h']; V third -> Vt transposed [b][h][s].
__global__ __launch_bounds__(256) void gemm_qkv(const ushort* __restrict__ xbf,
                                                const ushort* __restrict__ WtT,
                                                const float* __restrict__ bcat,
                                                ushort* __restrict__ QKV,
                                                ushort* __restrict__ Vt) {
  __shared__ __align__(16) char ldsA[8192], ldsB[8192];
  int tm = blockIdx.x, tn = blockIdx.y;
  floatx4 acc[4][4];
#pragma unroll
  for (int i = 0; i < 4; ++i)
#pragma unroll
    for (int j = 0; j < 4; ++j) acc[i][j] = (floatx4){0.f, 0.f, 0.f, 0.f};
  gemm_core(xbf + (size_t)tm * 128 * C_, C_, WtT + (size_t)tn * 128 * C_, C_,
            C_ / 32, ldsA, ldsB, acc);
  int tid = threadIdx.x, wave = tid >> 6, lane = tid & 63;
  int wm = wave >> 1, wn = wave & 1;
  int colb = lane & 15, rowq = (lane >> 4) * 4;
  if (tn < 32) {
    // Q/K region: row-major scalar stores
#pragma unroll
    for (int j = 0; j < 4; ++j) {
      int col = tn * 128 + wn * 64 + j * 16 + colb;
      float bv = bcat[col];
#pragma unroll
      for (int i = 0; i < 4; ++i) {
        int row = tm * 128 + wm * 64 + i * 16 + rowq;
#pragma unroll
        for (int r = 0; r < 4; ++r)
          QKV[(size_t)(row + r) * N3 + col] = f2bf(acc[i][j][r] + bv);
      }
    }
  } else {
    // V region: write transposed into Vt[b][h][s]; r-dim is s-contiguous
#pragma unroll
    for (int j = 0; j < 4; ++j) {
      int col = tn * 128 + wn * 64 + j * 16 + colb;   // 4096..6143
      int h = col - 4096;
      float bv = bcat[col];
#pragma unroll
      for (int i = 0; i < 4; ++i) {
        int row = tm * 128 + wm * 64 + i * 16 + rowq; // 0..8191, block stays in one b
        int b = row >> 11, s0 = row & 2047;
        ushort4 o4;
        o4.x = f2bf(acc[i][j][0] + bv);
        o4.y = f2bf(acc[i][j][1] + bv);
        o4.z = f2bf(acc[i][j][2] + bv);
        o4.w = f2bf(acc[i][j][3] + bv);
        *(ushort4*)(Vt + ((size_t)b * T_ + h) * T_ + s0) = o4;
      }
    }
  }
}

// ------------------------------------------------- GEMM: S = Q*K^T (causal)
// Compact grid: blockIdx.x = linear lower-triangle tile index (136/batch).
__global__ __launch_bounds__(256) void gemm_s(const ushort* __restrict__ QKV,
                                              float* __restrict__ S) {
  int l = blockIdx.x, b = blockIdx.y;
  int tm = (int)((sqrtf(8.f * l + 1.f) - 1.f) * 0.5f);
  while ((tm + 1) * (tm + 2) / 2 <= l) ++tm;
  while (tm * (tm + 1) / 2 > l) --tm;
  int tn = l - tm * (tm + 1) / 2;
  __shared__ __align__(16) char ldsA[8192], ldsB[8192];
  floatx4 acc[4][4];
#pragma unroll
  for (int i = 0; i < 4; ++i)
#pragma unroll
    for (int j = 0; j < 4; ++j) acc[i][j] = (floatx4){0.f, 0.f, 0.f, 0.f};
  const ushort* Ab = QKV + (size_t)b * T_ * N3 + (size_t)tm * 128 * N3;         // Q rows
  const ushort* Bb = QKV + (size_t)b * T_ * N3 + (size_t)tn * 128 * N3 + 2048;  // K rows
  gemm_core(Ab, N3, Bb, N3, T_ / 32, ldsA, ldsB, acc);
  float* Sb = S + (size_t)b * T_ * T_;
  int tid = threadIdx.x, wave = tid >> 6, lane = tid & 63;
  int wm = wave >> 1, wn = wave & 1;
  int colb = lane & 15, rowq = (lane >> 4) * 4;
#pragma unroll
  for (int i = 0; i < 4; ++i) {
    int row = tm * 128 + wm * 64 + i * 16 + rowq;
#pragma unroll
    for (int j = 0; j < 4; ++j) {
      int col = tn * 128 + wn * 64 + j * 16 + colb;
#pragma unroll
      for (int r = 0; r < 4; ++r)
        Sb[(size_t)(row + r) * T_ + col] = acc[i][j][r] * SCALE;
    }
  }
}

// ------------------------------------------------------------ causal softmax
__global__ __launch_bounds__(256) void softmax_causal(const float* __restrict__ S,
                                                      ushort* __restrict__ P) {
  int t = blockIdx.x, b = blockIdx.y;
  int tid = threadIdx.x;
  const float* srow = S + ((size_t)b * T_ + t) * T_;
  ushort* prow = P + ((size_t)b * T_ + t) * T_;
  int band = ((t >> 7) + 1) << 7;    // round_up(t+1, 128) == O-GEMM k_end
  float xv[8];
  float m = -INFINITY;
#pragma unroll
  for (int c = 0; c < 2; ++c) {
    int s0 = c * 1024 + tid * 4;
    float* xs = xv + c * 4;
    if (s0 < band) {
      float4 v = *(const float4*)(srow + s0);
      xs[0] = (s0 + 0 <= t) ? v.x : -INFINITY;  // scale applied in gemm_s
      xs[1] = (s0 + 1 <= t) ? v.y : -INFINITY;
      xs[2] = (s0 + 2 <= t) ? v.z : -INFINITY;
      xs[3] = (s0 + 3 <= t) ? v.w : -INFINITY;
      m = fmaxf(fmaxf(fmaxf(xs[0], xs[1]), fmaxf(xs[2], xs[3])), m);
    } else {
      xs[0] = xs[1] = xs[2] = xs[3] = -INFINITY;
    }
  }
  __shared__ float sm4[4];
  int wid = tid >> 6, ln = tid & 63;
#pragma unroll
  for (int o = 32; o; o >>= 1) m = fmaxf(m, __shfl_xor(m, o));
  if (ln == 0) sm4[wid] = m;
  __syncthreads();
  m = fmaxf(fmaxf(sm4[0], sm4[1]), fmaxf(sm4[2], sm4[3]));
  __syncthreads();
  float sum = 0.f;
#pragma unroll
  for (int k = 0; k < 8; ++k) { xv[k] = __expf(xv[k] - m); sum += xv[k]; }
#pragma unroll
  for (int o = 32; o; o >>= 1) sum += __shfl_xor(sum, o);
  if (ln == 0) sm4[wid] = sum;
  __syncthreads();
  sum = sm4[0] + sm4[1] + sm4[2] + sm4[3];
  float inv = 1.0f / sum;
#pragma unroll
  for (int c = 0; c < 2; ++c) {
    int s0 = c * 1024 + tid * 4;
    if (s0 < band) {
      ushort4 o4;
      o4.x = f2bf(xv[c * 4 + 0] * inv);
      o4.y = f2bf(xv[c * 4 + 1] * inv);
      o4.z = f2bf(xv[c * 4 + 2] * inv);
      o4.w = f2bf(xv[c * 4 + 3] * inv);
      *(ushort4*)(prow + s0) = o4;
    }
  }
}

// ------------------------------------------------ GEMM: O = P*V (k <= diag)
// Longest tile-rows (tm=15, 64 k-steps) dispatch FIRST: tm = 15 - blockIdx.y.
__global__ __launch_bounds__(256) void gemm_o(const ushort* __restrict__ P,
                                              const ushort* __restrict__ Vt,
                                              float* __restrict__ O) {
  int tn = blockIdx.x, tm = 15 - blockIdx.y, b = blockIdx.z;
  __shared__ __align__(16) char ldsA[8192], ldsB[8192];
  floatx4 acc[4][4];
#pragma unroll
  for (int i = 0; i < 4; ++i)
#pragma unroll
    for (int j = 0; j < 4; ++j) acc[i][j] = (floatx4){0.f, 0.f, 0.f, 0.f};
  const ushort* Ab = P + (size_t)b * T_ * T_ + (size_t)tm * 128 * T_;
  const ushort* Bb = Vt + (size_t)b * T_ * T_ + (size_t)tn * 128 * T_;
  gemm_core(Ab, T_, Bb, T_, (tm + 1) * 4, ldsA, ldsB, acc);  // k_end = (tm+1)*128
  float* Ob = O + (size_t)b * T_ * T_;
  int tid = threadIdx.x, wave = tid >> 6, lane = tid & 63;
  int wm = wave >> 1, wn = wave & 1;
  int colb = lane & 15, rowq = (lane >> 4) * 4;
#pragma unroll
  for (int i = 0; i < 4; ++i) {
    int row = tm * 128 + wm * 64 + i * 16 + rowq;
#pragma unroll
    for (int j = 0; j < 4; ++j) {
      int col = tn * 128 + wn * 64 + j * 16 + colb;
#pragma unroll
      for (int r = 0; r < 4; ++r)
        Ob[(size_t)(row + r) * T_ + col] = acc[i][j][r];
    }
  }
}

// ---------------------------------------------------------------- launcher
extern "C" void kernel_launch(void* const* d_in, const int* in_sizes, int n_in,
                              void* d_out, int out_size, void* d_ws, size_t ws_size,
                              hipStream_t stream) {
  (void)in_sizes; (void)n_in; (void)out_size; (void)ws_size;
  const float* x  = (const float*)d_in[0];
  const float* Wq = (const float*)d_in[1];
  const float* bq = (const float*)d_in[2];
  const float* Wk = (const float*)d_in[3];
  const float* bk = (const float*)d_in[4];
  const float* Wv = (const float*)d_in[5];
  const float* bv = (const float*)d_in[6];

  char* ws = (char*)d_ws;
  ushort* xbf  = (ushort*)(ws + 0);           // 16,777,216 B
  ushort* WtT  = (ushort*)(ws + 16777216);    // 12,582,912 B
  float*  bcat = (float*) (ws + 29360128);    //     24,576 B
  ushort* QKV  = (ushort*)(ws + 29384704);    // 100,663,296 B (V third unused)
  ushort* P    = (ushort*)(ws + 130048000);   // 33,554,432 B
  ushort* Vt   = (ushort*)(ws + 163602432);   // 33,554,432 B  (end ~188 MiB)

  float* S = (float*)d_out;   // S scratch lives in d_out, later overwritten by O
  float* O = (float*)d_out;

  cast_x_kernel  <<<8192, 256, 0, stream>>>(x, xbf);
  wcast_t_kernel <<<dim3(32, 192), dim3(32, 8), 0, stream>>>(Wq, Wk, Wv, WtT);
  bias_cat_kernel<<<24, 256, 0, stream>>>(bq, bk, bv, bcat);
  gemm_qkv       <<<dim3(64, 48), 256, 0, stream>>>(xbf, WtT, bcat, QKV, Vt);
  gemm_s         <<<dim3(136, 4), 256, 0, stream>>>(QKV, S);
  softmax_causal <<<dim3(2048, 4), 256, 0, stream>>>(S, P);
  gemm_o         <<<dim3(16, 16, 4), 256, 0, stream>>>(P, Vt, O);
}

// Round 4
// 430.715 us; speedup vs baseline: 1.0589x; 1.0589x over previous
//
#include <hip/hip_runtime.h>

// AttentionHead  B=4, T=2048, C=1024, HEAD=2048, fp32 in/out.
// Round 3: r1/r2 A-B proved the LDS swizzle was neutral and the branched
// Vt-fused epilogue caused the whole gemm_qkv regression (VGPR 84->116,
// FETCH +14.6MB from partial-line write-allocate on scattered ushort4 Vt
// stores). Fix: split into gemm_qk (r0 scalar epilogue, QK ld=4096) and
// gemm_v (LDS-transposed epilogue -> 256B-coalesced Vt stores).

#define T_    2048
#define C_    1024
#define B_    4
#define NQK   4096
#define SCALE 0.03125f   // C^-0.5 = 1/32 exactly

typedef __attribute__((ext_vector_type(4))) float floatx4;
typedef __attribute__((ext_vector_type(8))) short short8;
typedef __attribute__((ext_vector_type(8))) unsigned short ushortx8;

__device__ __forceinline__ unsigned short f2bf(float f) {
  unsigned int u = __float_as_uint(f);
  unsigned int r = (u + 0x7fffu + ((u >> 16) & 1u)) >> 16;  // RNE
  return (unsigned short)r;
}

// ---------------------------------------------------------------- cast x
__global__ void cast_x_kernel(const float* __restrict__ x, ushort* __restrict__ xbf) {
  int i = blockIdx.x * 256 + threadIdx.x;          // over N/4 = 2097152
  float4 v = ((const float4*)x)[i];
  ushort4 o;
  o.x = f2bf(v.x); o.y = f2bf(v.y); o.z = f2bf(v.z); o.w = f2bf(v.w);
  ((ushort4*)xbf)[i] = o;
}

// ------------------------------------------- cast + transpose W -> WtT[n][k]
__global__ void wcast_t_kernel(const float* __restrict__ Wq, const float* __restrict__ Wk,
                               const float* __restrict__ Wv, ushort* __restrict__ WtT) {
  int k0 = blockIdx.x * 32;           // over C=1024
  int n0 = blockIdx.y * 32;           // over 6144
  const float* W = (n0 < 2048) ? Wq : (n0 < 4096 ? Wk : Wv);
  int nl0 = n0 & 2047;
  __shared__ ushort tile[32][33];
  int tx = threadIdx.x, ty = threadIdx.y;
  for (int r = ty; r < 32; r += 8)
    tile[r][tx] = f2bf(W[(size_t)(k0 + r) * 2048 + nl0 + tx]);
  __syncthreads();
  for (int r = ty; r < 32; r += 8)
    WtT[(size_t)(n0 + r) * 1024 + k0 + tx] = tile[tx][r];
}

// ---------------------------------------------------------------- bias concat
__global__ void bias_cat_kernel(const float* __restrict__ bq, const float* __restrict__ bk,
                                const float* __restrict__ bv, float* __restrict__ bcat) {
  int i = blockIdx.x * 256 + threadIdx.x;
  if (i < 6144) {
    const float* s = (i < 2048) ? bq : (i < 4096 ? bk : bv);
    bcat[i] = s[i & 2047];
  }
}

// ------------------------------------------------------- GEMM core (m97 BT)
__device__ __forceinline__ void stage128x32(const ushort* g, int ld, char* lds,
                                            int wave, int lane) {
#pragma unroll
  for (int c = 0; c < 2; ++c) {
    int chunk = wave + 4 * c;                       // 8 chunks of 16 rows
    const ushort* gaddr = g + (size_t)(chunk * 16 + (lane >> 2)) * ld + (lane & 3) * 8;
    char* laddr = lds + chunk * 1024;               // wave-uniform
    __builtin_amdgcn_global_load_lds((const __attribute__((address_space(1))) unsigned int*)gaddr,
                                     (__attribute__((address_space(3))) unsigned int*)laddr,
                                     16, 0, 0);
  }
}

__device__ __forceinline__ void gemm_core(const ushort* A, int lda,
                                          const ushort* Bm, int ldb, int ksteps,
                                          char* ldsA, char* ldsB, floatx4 acc[4][4]) {
  int tid = threadIdx.x;
  int wave = tid >> 6, lane = tid & 63;
  int wm = wave >> 1, wn = wave & 1;
  int koff2 = ((lane >> 4) * 8) * 2;   // byte offset of k-fragment
  int rbase = lane & 15;
  for (int s = 0; s < ksteps; ++s) {
    __syncthreads();                              // LDS reads of prev iter done
    stage128x32(A + s * 32, lda, ldsA, wave, lane);
    stage128x32(Bm + s * 32, ldb, ldsB, wave, lane);
    __syncthreads();                              // vmcnt drain before reads
    short8 af[4], bf[4];
#pragma unroll
    for (int i = 0; i < 4; ++i) {
      af[i] = *(const short8*)(ldsA + (wm * 64 + i * 16 + rbase) * 64 + koff2);
      bf[i] = *(const short8*)(ldsB + (wn * 64 + i * 16 + rbase) * 64 + koff2);
    }
#pragma unroll
    for (int i = 0; i < 4; ++i)
#pragma unroll
      for (int j = 0; j < 4; ++j)
        acc[i][j] = __builtin_amdgcn_mfma_f32_16x16x32_bf16(af[i], bf[j], acc[i][j], 0, 0, 0);
  }
}

// ------------------------------------------- GEMM: Q,K projection (ld=4096)
__global__ __launch_bounds__(256) void gemm_qk(const ushort* __restrict__ xbf,
                                               const ushort* __restrict__ WtT,
                                               const float* __restrict__ bcat,
                                               ushort* __restrict__ QK) {
  __shared__ __align__(16) char ldsA[8192], ldsB[8192];
  int tm = blockIdx.x, tn = blockIdx.y;          // tn in [0,32)
  floatx4 acc[4][4];
#pragma unroll
  for (int i = 0; i < 4; ++i)
#pragma unroll
    for (int j = 0; j < 4; ++j) acc[i][j] = (floatx4){0.f, 0.f, 0.f, 0.f};
  gemm_core(xbf + (size_t)tm * 128 * C_, C_, WtT + (size_t)tn * 128 * C_, C_,
            C_ / 32, ldsA, ldsB, acc);
  int tid = threadIdx.x, wave = tid >> 6, lane = tid & 63;
  int wm = wave >> 1, wn = wave & 1;
  int colb = lane & 15, rowq = (lane >> 4) * 4;
#pragma unroll
  for (int j = 0; j < 4; ++j) {
    int col = tn * 128 + wn * 64 + j * 16 + colb;
    float bv = bcat[col];
#pragma unroll
    for (int i = 0; i < 4; ++i) {
      int row = tm * 128 + wm * 64 + i * 16 + rowq;
#pragma unroll
      for (int r = 0; r < 4; ++r)
        QK[(size_t)(row + r) * NQK + col] = f2bf(acc[i][j][r] + bv);
    }
  }
}

// --------------------------- GEMM: V projection, writes Vt[b][h][s] directly
// Epilogue round-trips the 128x128 tile through LDS (stride 136 ushorts:
// rows 16B-aligned, 2-way-free write banks) so Vt stores are 256B runs.
__global__ __launch_bounds__(256) void gemm_v(const ushort* __restrict__ xbf,
                                              const ushort* __restrict__ WtT,
                                              const float* __restrict__ bcat,
                                              ushort* __restrict__ Vt) {
  __shared__ __align__(16) char lds[128 * 136 * 2];   // 34816 B; first 16KB = staging
  char* ldsA = lds;
  char* ldsB = lds + 8192;
  int tm = blockIdx.x, tn = blockIdx.y;          // tn in [0,16)
  floatx4 acc[4][4];
#pragma unroll
  for (int i = 0; i < 4; ++i)
#pragma unroll
    for (int j = 0; j < 4; ++j) acc[i][j] = (floatx4){0.f, 0.f, 0.f, 0.f};
  gemm_core(xbf + (size_t)tm * 128 * C_, C_, WtT + (size_t)(32 + tn) * 128 * C_, C_,
            C_ / 32, ldsA, ldsB, acc);
  int tid = threadIdx.x, wave = tid >> 6, lane = tid & 63;
  int wm = wave >> 1, wn = wave & 1;
  int colb = lane & 15, rowq = (lane >> 4) * 4;
  __syncthreads();                               // staging reads all consumed
  ushort* tileT = (ushort*)lds;                  // [h_local][s_local], stride 136
#pragma unroll
  for (int j = 0; j < 4; ++j) {
    int h = wn * 64 + j * 16 + colb;
    float bv = bcat[4096 + tn * 128 + h];
#pragma unroll
    for (int i = 0; i < 4; ++i) {
      int s = wm * 64 + i * 16 + rowq;
      ushort4 o4;
      o4.x = f2bf(acc[i][j][0] + bv);
      o4.y = f2bf(acc[i][j][1] + bv);
      o4.z = f2bf(acc[i][j][2] + bv);
      o4.w = f2bf(acc[i][j][3] + bv);
      *(ushort4*)(tileT + h * 136 + s) = o4;
    }
  }
  __syncthreads();
  int b = tm >> 4, sbase = (tm & 15) * 128;
  int hr = tid >> 4, sc = (tid & 15) * 8;
#pragma unroll
  for (int it = 0; it < 8; ++it) {
    int h = it * 16 + hr;
    ushortx8 v = *(const ushortx8*)(tileT + h * 136 + sc);
    *(ushortx8*)(Vt + ((size_t)b * T_ + tn * 128 + h) * T_ + sbase + sc) = v;
  }
}

// ------------------------------------------------- GEMM: S = Q*K^T (causal)
__global__ __launch_bounds__(256) void gemm_s(const ushort* __restrict__ QK,
                                              float* __restrict__ S) {
  int l = blockIdx.x, b = blockIdx.y;
  int tm = (int)((sqrtf(8.f * l + 1.f) - 1.f) * 0.5f);
  while ((tm + 1) * (tm + 2) / 2 <= l) ++tm;
  while (tm * (tm + 1) / 2 > l) --tm;
  int tn = l - tm * (tm + 1) / 2;
  __shared__ __align__(16) char ldsA[8192], ldsB[8192];
  floatx4 acc[4][4];
#pragma unroll
  for (int i = 0; i < 4; ++i)
#pragma unroll
    for (int j = 0; j < 4; ++j) acc[i][j] = (floatx4){0.f, 0.f, 0.f, 0.f};
  const ushort* Ab = QK + (size_t)b * T_ * NQK + (size_t)tm * 128 * NQK;         // Q rows
  const ushort* Bb = QK + (size_t)b * T_ * NQK + (size_t)tn * 128 * NQK + 2048;  // K rows
  gemm_core(Ab, NQK, Bb, NQK, T_ / 32, ldsA, ldsB, acc);
  float* Sb = S + (size_t)b * T_ * T_;
  int tid = threadIdx.x, wave = tid >> 6, lane = tid & 63;
  int wm = wave >> 1, wn = wave & 1;
  int colb = lane & 15, rowq = (lane >> 4) * 4;
#pragma unroll
  for (int i = 0; i < 4; ++i) {
    int row = tm * 128 + wm * 64 + i * 16 + rowq;
#pragma unroll
    for (int j = 0; j < 4; ++j) {
      int col = tn * 128 + wn * 64 + j * 16 + colb;
#pragma unroll
      for (int r = 0; r < 4; ++r)
        Sb[(size_t)(row + r) * T_ + col] = acc[i][j][r] * SCALE;
    }
  }
}

// ------------------------------------------------------------ causal softmax
__global__ __launch_bounds__(256) void softmax_causal(const float* __restrict__ S,
                                                      ushort* __restrict__ P) {
  int t = blockIdx.x, b = blockIdx.y;
  int tid = threadIdx.x;
  const float* srow = S + ((size_t)b * T_ + t) * T_;
  ushort* prow = P + ((size_t)b * T_ + t) * T_;
  int band = ((t >> 7) + 1) << 7;    // round_up(t+1, 128) == O-GEMM k_end
  float xv[8];
  float m = -INFINITY;
#pragma unroll
  for (int c = 0; c < 2; ++c) {
    int s0 = c * 1024 + tid * 4;
    float* xs = xv + c * 4;
    if (s0 < band) {
      float4 v = *(const float4*)(srow + s0);
      xs[0] = (s0 + 0 <= t) ? v.x : -INFINITY;  // scale applied in gemm_s
      xs[1] = (s0 + 1 <= t) ? v.y : -INFINITY;
      xs[2] = (s0 + 2 <= t) ? v.z : -INFINITY;
      xs[3] = (s0 + 3 <= t) ? v.w : -INFINITY;
      m = fmaxf(fmaxf(fmaxf(xs[0], xs[1]), fmaxf(xs[2], xs[3])), m);
    } else {
      xs[0] = xs[1] = xs[2] = xs[3] = -INFINITY;
    }
  }
  __shared__ float sm4[4];
  int wid = tid >> 6, ln = tid & 63;
#pragma unroll
  for (int o = 32; o; o >>= 1) m = fmaxf(m, __shfl_xor(m, o));
  if (ln == 0) sm4[wid] = m;
  __syncthreads();
  m = fmaxf(fmaxf(sm4[0], sm4[1]), fmaxf(sm4[2], sm4[3]));
  __syncthreads();
  float sum = 0.f;
#pragma unroll
  for (int k = 0; k < 8; ++k) { xv[k] = __expf(xv[k] - m); sum += xv[k]; }
#pragma unroll
  for (int o = 32; o; o >>= 1) sum += __shfl_xor(sum, o);
  if (ln == 0) sm4[wid] = sum;
  __syncthreads();
  sum = sm4[0] + sm4[1] + sm4[2] + sm4[3];
  float inv = 1.0f / sum;
#pragma unroll
  for (int c = 0; c < 2; ++c) {
    int s0 = c * 1024 + tid * 4;
    if (s0 < band) {
      ushort4 o4;
      o4.x = f2bf(xv[c * 4 + 0] * inv);
      o4.y = f2bf(xv[c * 4 + 1] * inv);
      o4.z = f2bf(xv[c * 4 + 2] * inv);
      o4.w = f2bf(xv[c * 4 + 3] * inv);
      *(ushort4*)(prow + s0) = o4;
    }
  }
}

// ------------------------------------------------ GEMM: O = P*V (k <= diag)
__global__ __launch_bounds__(256) void gemm_o(const ushort* __restrict__ P,
                                              const ushort* __restrict__ Vt,
                                              float* __restrict__ O) {
  int tn = blockIdx.x, tm = 15 - blockIdx.y, b = blockIdx.z;  // longest-first
  __shared__ __align__(16) char ldsA[8192], ldsB[8192];
  floatx4 acc[4][4];
#pragma unroll
  for (int i = 0; i < 4; ++i)
#pragma unroll
    for (int j = 0; j < 4; ++j) acc[i][j] = (floatx4){0.f, 0.f, 0.f, 0.f};
  const ushort* Ab = P + (size_t)b * T_ * T_ + (size_t)tm * 128 * T_;
  const ushort* Bb = Vt + (size_t)b * T_ * T_ + (size_t)tn * 128 * T_;
  gemm_core(Ab, T_, Bb, T_, (tm + 1) * 4, ldsA, ldsB, acc);  // k_end = (tm+1)*128
  float* Ob = O + (size_t)b * T_ * T_;
  int tid = threadIdx.x, wave = tid >> 6, lane = tid & 63;
  int wm = wave >> 1, wn = wave & 1;
  int colb = lane & 15, rowq = (lane >> 4) * 4;
#pragma unroll
  for (int i = 0; i < 4; ++i) {
    int row = tm * 128 + wm * 64 + i * 16 + rowq;
#pragma unroll
    for (int j = 0; j < 4; ++j) {
      int col = tn * 128 + wn * 64 + j * 16 + colb;
#pragma unroll
      for (int r = 0; r < 4; ++r)
        Ob[(size_t)(row + r) * T_ + col] = acc[i][j][r];
    }
  }
}

// ---------------------------------------------------------------- launcher
extern "C" void kernel_launch(void* const* d_in, const int* in_sizes, int n_in,
                              void* d_out, int out_size, void* d_ws, size_t ws_size,
                              hipStream_t stream) {
  (void)in_sizes; (void)n_in; (void)out_size; (void)ws_size;
  const float* x  = (const float*)d_in[0];
  const float* Wq = (const float*)d_in[1];
  const float* bq = (const float*)d_in[2];
  const float* Wk = (const float*)d_in[3];
  const float* bk = (const float*)d_in[4];
  const float* Wv = (const float*)d_in[5];
  const float* bv = (const float*)d_in[6];

  char* ws = (char*)d_ws;
  ushort* xbf  = (ushort*)(ws + 0);           // 16,777,216 B
  ushort* WtT  = (ushort*)(ws + 16777216);    // 12,582,912 B
  float*  bcat = (float*) (ws + 29360128);    //     24,576 B
  ushort* QK   = (ushort*)(ws + 29384704);    // 67,108,864 B  [8192][4096]
  ushort* P    = (ushort*)(ws + 96493568);    // 33,554,432 B
  ushort* Vt   = (ushort*)(ws + 130048000);   // 33,554,432 B  (end ~156 MiB)

  float* S = (float*)d_out;   // S scratch lives in d_out, later overwritten by O
  float* O = (float*)d_out;

  cast_x_kernel  <<<8192, 256, 0, stream>>>(x, xbf);
  wcast_t_kernel <<<dim3(32, 192), dim3(32, 8), 0, stream>>>(Wq, Wk, Wv, WtT);
  bias_cat_kernel<<<24, 256, 0, stream>>>(bq, bk, bv, bcat);
  gemm_qk        <<<dim3(64, 32), 256, 0, stream>>>(xbf, WtT, bcat, QK);
  gemm_v         <<<dim3(64, 16), 256, 0, stream>>>(xbf, WtT, bcat, Vt);
  gemm_s         <<<dim3(136, 4), 256, 0, stream>>>(QK, S);
  softmax_causal <<<dim3(2048, 4), 256, 0, stream>>>(S, P);
  gemm_o         <<<dim3(16, 16, 4), 256, 0, stream>>>(P, Vt, O);
}